// Round 2
// baseline (219.452 us; speedup 1.0000x reference)
//
#include <hip/hip_runtime.h>
#include <math.h>

#define SAMPLE_RATE 44100.0
#define R_PARAM 0.5
#define F_PARAM 1000.0

typedef float f32x4 __attribute__((ext_vector_type(4)));

// ---------------------------------------------------------------------------
// Prologue: single thread builds the combined affine map from the 4 scalars.
// ws layout (floats): [0..15] Mc = M_inv@M_fwd (row-major),
//                     [16..19] va = M_inv@b_a, [20..23] vb = M_inv@b_1ma,
//                     [24] gain
// ---------------------------------------------------------------------------
__device__ void inv4x4(const double A[4][4], double Ainv[4][4]) {
    double M[4][8];
    for (int i = 0; i < 4; ++i) {
        for (int j = 0; j < 4; ++j) { M[i][j] = A[i][j]; M[i][4 + j] = (i == j) ? 1.0 : 0.0; }
    }
    for (int col = 0; col < 4; ++col) {
        int p = col;
        for (int r = col + 1; r < 4; ++r)
            if (fabs(M[r][col]) > fabs(M[p][col])) p = r;
        if (p != col)
            for (int j = 0; j < 8; ++j) { double t = M[col][j]; M[col][j] = M[p][j]; M[p][j] = t; }
        double d = 1.0 / M[col][col];
        for (int j = 0; j < 8; ++j) M[col][j] *= d;
        for (int r = 0; r < 4; ++r) {
            if (r == col) continue;
            double f = M[r][col];
            for (int j = 0; j < 8; ++j) M[r][j] -= f * M[col][j];
        }
    }
    for (int i = 0; i < 4; ++i)
        for (int j = 0; j < 4; ++j) Ainv[i][j] = M[i][4 + j];
}

__global__ void moog_prologue(const float* __restrict__ gf,
                              const float* __restrict__ gr,
                              const float* __restrict__ gain,
                              const float* __restrict__ alpha,
                              float* __restrict__ ws) {
    const double k  = 1.0 / SAMPLE_RATE;
    const double w  = 2.0 * M_PI * (double)gf[0] * F_PARAM;
    const double grv = (double)gr[0];
    const double al  = (double)alpha[0];
    const double gn  = (double)gain[0];

    double A[4][4] = {
        { -w, 0.0, 0.0, -4.0 * w * grv * R_PARAM },
        {  w,  -w, 0.0, 0.0 },
        { 0.0,  w,  -w, 0.0 },
        { 0.0, 0.0,  w,  -w }
    };

    double kA2[4][4];
    for (int i = 0; i < 4; ++i)
        for (int j = 0; j < 4; ++j) kA2[i][j] = 0.5 * k * A[i][j];

    // I - kA2*alpha
    double Mlhs[4][4];
    for (int i = 0; i < 4; ++i)
        for (int j = 0; j < 4; ++j)
            Mlhs[i][j] = ((i == j) ? 1.0 : 0.0) - kA2[i][j] * al;

    double Minv[4][4];
    inv4x4(Mlhs, Minv);

    // M_fwd = I + 2*kA2 - kA2*alpha = I + kA2*(2 - alpha)
    double Mfwd[4][4];
    for (int i = 0; i < 4; ++i)
        for (int j = 0; j < 4; ++j)
            Mfwd[i][j] = ((i == j) ? 1.0 : 0.0) + kA2[i][j] * (2.0 - al);

    // Mc = Minv @ Mfwd
    double Mc[4][4];
    for (int i = 0; i < 4; ++i)
        for (int j = 0; j < 4; ++j) {
            double s = 0.0;
            for (int m = 0; m < 4; ++m) s += Minv[i][m] * Mfwd[m][j];
            Mc[i][j] = s;
        }

    // b vectors: kb2 = k*Bv/2 with Bv = [w,0,0,0]^T
    double kb2_0 = 0.5 * k * w;
    double ba0  = kb2_0 * al;                 // b_a   = kb2*alpha
    double b1m0 = kb2_0 * (1.0 - 0.5 * al);   // b_1ma = kb2*(1 - alpha/2)

    // va = Minv @ b_a (only first component of b nonzero), vb likewise
    for (int i = 0; i < 4; ++i) {
        for (int j = 0; j < 4; ++j) ws[4 * i + j] = (float)Mc[i][j];
        ws[16 + i] = (float)(Minv[i][0] * ba0);
        ws[20 + i] = (float)(Minv[i][0] * b1m0);
    }
    ws[24] = (float)gn;
}

// ---------------------------------------------------------------------------
// Vectorized main kernel: 4 samples per thread, every stream 16 B/lane.
// out layout: [0,B) = y_n ; [B,5B) = x_n (4 per sample) ; [5B,6B) = u_n copy
// Requires B % 4 == 0 (alignment of the f32x4 views of out).
// ---------------------------------------------------------------------------
__global__ __launch_bounds__(256) void moog_main4(
        const f32x4* __restrict__ u4,    // u_n as quads
        const f32x4* __restrict__ x4,    // x_n1, one quad per sample
        const f32x4* __restrict__ u14,   // u_n1 as quads
        const float* __restrict__ ws,
        float* __restrict__ out,
        int B) {
    __shared__ float c[25];
    int t = threadIdx.x;
    if (t < 25) c[t] = ws[t];
    __syncthreads();

    int nq = B >> 2;
    int q = blockIdx.x * blockDim.x + t;
    if (q >= nq) return;

    f32x4 u  = u4[q];
    f32x4 u1 = u14[q];
    int s = q << 2;
    f32x4 xa = x4[s + 0];
    f32x4 xb = x4[s + 1];
    f32x4 xc = x4[s + 2];
    f32x4 xd = x4[s + 3];

    // Per-sample math: expression order identical to the verified scalar kernel.
    f32x4 y;

    float a0 = c[0]  * xa.x + c[1]  * xa.y + c[2]  * xa.z + c[3]  * xa.w + c[16] * u.x + c[20] * u1.x;
    float a1 = c[4]  * xa.x + c[5]  * xa.y + c[6]  * xa.z + c[7]  * xa.w + c[17] * u.x + c[21] * u1.x;
    float a2 = c[8]  * xa.x + c[9]  * xa.y + c[10] * xa.z + c[11] * xa.w + c[18] * u.x + c[22] * u1.x;
    float a3 = c[12] * xa.x + c[13] * xa.y + c[14] * xa.z + c[15] * xa.w + c[19] * u.x + c[23] * u1.x;
    y.x = c[24] * a3;

    float b0 = c[0]  * xb.x + c[1]  * xb.y + c[2]  * xb.z + c[3]  * xb.w + c[16] * u.y + c[20] * u1.y;
    float b1 = c[4]  * xb.x + c[5]  * xb.y + c[6]  * xb.z + c[7]  * xb.w + c[17] * u.y + c[21] * u1.y;
    float b2 = c[8]  * xb.x + c[9]  * xb.y + c[10] * xb.z + c[11] * xb.w + c[18] * u.y + c[22] * u1.y;
    float b3 = c[12] * xb.x + c[13] * xb.y + c[14] * xb.z + c[15] * xb.w + c[19] * u.y + c[23] * u1.y;
    y.y = c[24] * b3;

    float d0 = c[0]  * xc.x + c[1]  * xc.y + c[2]  * xc.z + c[3]  * xc.w + c[16] * u.z + c[20] * u1.z;
    float d1 = c[4]  * xc.x + c[5]  * xc.y + c[6]  * xc.z + c[7]  * xc.w + c[17] * u.z + c[21] * u1.z;
    float d2 = c[8]  * xc.x + c[9]  * xc.y + c[10] * xc.z + c[11] * xc.w + c[18] * u.z + c[22] * u1.z;
    float d3 = c[12] * xc.x + c[13] * xc.y + c[14] * xc.z + c[15] * xc.w + c[19] * u.z + c[23] * u1.z;
    y.z = c[24] * d3;

    float e0 = c[0]  * xd.x + c[1]  * xd.y + c[2]  * xd.z + c[3]  * xd.w + c[16] * u.w + c[20] * u1.w;
    float e1 = c[4]  * xd.x + c[5]  * xd.y + c[6]  * xd.z + c[7]  * xd.w + c[17] * u.w + c[21] * u1.w;
    float e2 = c[8]  * xd.x + c[9]  * xd.y + c[10] * xd.z + c[11] * xd.w + c[18] * u.w + c[22] * u1.w;
    float e3 = c[12] * xd.x + c[13] * xd.y + c[14] * xd.z + c[15] * xd.w + c[19] * u.w + c[23] * u1.w;
    y.w = c[24] * e3;

    f32x4* oy = (f32x4*)out;                         // y_n, 4 samples/store
    f32x4* ox = (f32x4*)(out + (size_t)B);           // x_n, 1 sample/store
    f32x4* ou = (f32x4*)(out + 5 * (size_t)B);       // u_n passthrough

    f32x4 va = {a0, a1, a2, a3};
    f32x4 vb = {b0, b1, b2, b3};
    f32x4 vd = {d0, d1, d2, d3};
    f32x4 ve = {e0, e1, e2, e3};

    __builtin_nontemporal_store(va, &ox[s + 0]);
    __builtin_nontemporal_store(vb, &ox[s + 1]);
    __builtin_nontemporal_store(vd, &ox[s + 2]);
    __builtin_nontemporal_store(ve, &ox[s + 3]);
    __builtin_nontemporal_store(y, &oy[q]);
    __builtin_nontemporal_store(u, &ou[q]);
}

// ---------------------------------------------------------------------------
// Scalar fallback (the previous verified kernel) for B % 4 != 0.
// ---------------------------------------------------------------------------
__global__ __launch_bounds__(256) void moog_main(
        const float*  __restrict__ u_n,
        const float4* __restrict__ x_n1,
        const float*  __restrict__ u_n1,
        const float*  __restrict__ ws,
        float* __restrict__ out,
        int B) {
    __shared__ float c[25];
    int t = threadIdx.x;
    if (t < 25) c[t] = ws[t];
    __syncthreads();

    int i = blockIdx.x * blockDim.x + t;
    if (i >= B) return;

    float4 x = x_n1[i];
    float u  = u_n[i];
    float u1 = u_n1[i];

    float r0 = c[0]  * x.x + c[1]  * x.y + c[2]  * x.z + c[3]  * x.w + c[16] * u + c[20] * u1;
    float r1 = c[4]  * x.x + c[5]  * x.y + c[6]  * x.z + c[7]  * x.w + c[17] * u + c[21] * u1;
    float r2 = c[8]  * x.x + c[9]  * x.y + c[10] * x.z + c[11] * x.w + c[18] * u + c[22] * u1;
    float r3 = c[12] * x.x + c[13] * x.y + c[14] * x.z + c[15] * x.w + c[19] * u + c[23] * u1;

    out[i] = c[24] * r3;                         // y_n
    float* ox = out + (size_t)B + 4 * (size_t)i; // x_n block (scalar stores, no alignment assumption)
    ox[0] = r0; ox[1] = r1; ox[2] = r2; ox[3] = r3;
    out[5 * (size_t)B + i] = u;                  // u_n passthrough
}

extern "C" void kernel_launch(void* const* d_in, const int* in_sizes, int n_in,
                              void* d_out, int out_size, void* d_ws, size_t ws_size,
                              hipStream_t stream) {
    const float* u_n   = (const float*)d_in[0];
    const float* x_n1  = (const float*)d_in[1];
    const float* u_n1  = (const float*)d_in[2];
    const float* gf    = (const float*)d_in[3];
    const float* gr    = (const float*)d_in[4];
    const float* gain  = (const float*)d_in[5];
    const float* alpha = (const float*)d_in[6];

    int B = in_sizes[0];
    float* ws = (float*)d_ws;

    moog_prologue<<<1, 1, 0, stream>>>(gf, gr, gain, alpha, ws);

    int block = 256;
    if ((B & 3) == 0) {
        int nq = B >> 2;
        int grid = (nq + block - 1) / block;
        moog_main4<<<grid, block, 0, stream>>>((const f32x4*)u_n, (const f32x4*)x_n1,
                                               (const f32x4*)u_n1, ws,
                                               (float*)d_out, B);
    } else {
        int grid = (B + block - 1) / block;
        moog_main<<<grid, block, 0, stream>>>(u_n, (const float4*)x_n1, u_n1, ws,
                                              (float*)d_out, B);
    }
}

// Round 3
// 195.396 us; speedup vs baseline: 1.1231x; 1.1231x over previous
//
#include <hip/hip_runtime.h>
#include <math.h>

#define SAMPLE_RATE 44100.0
#define R_PARAM 0.5
#define F_PARAM 1000.0

typedef float f32x4 __attribute__((ext_vector_type(4)));

// ---------------------------------------------------------------------------
// Prologue: single thread builds the combined affine map from the 4 scalars.
// ws layout (floats): [0..15] Mc = M_inv@M_fwd (row-major),
//                     [16..19] va = M_inv@b_a, [20..23] vb = M_inv@b_1ma,
//                     [24] gain
// ---------------------------------------------------------------------------
__device__ void inv4x4(const double A[4][4], double Ainv[4][4]) {
    double M[4][8];
    for (int i = 0; i < 4; ++i) {
        for (int j = 0; j < 4; ++j) { M[i][j] = A[i][j]; M[i][4 + j] = (i == j) ? 1.0 : 0.0; }
    }
    for (int col = 0; col < 4; ++col) {
        int p = col;
        for (int r = col + 1; r < 4; ++r)
            if (fabs(M[r][col]) > fabs(M[p][col])) p = r;
        if (p != col)
            for (int j = 0; j < 8; ++j) { double t = M[col][j]; M[col][j] = M[p][j]; M[p][j] = t; }
        double d = 1.0 / M[col][col];
        for (int j = 0; j < 8; ++j) M[col][j] *= d;
        for (int r = 0; r < 4; ++r) {
            if (r == col) continue;
            double f = M[r][col];
            for (int j = 0; j < 8; ++j) M[r][j] -= f * M[col][j];
        }
    }
    for (int i = 0; i < 4; ++i)
        for (int j = 0; j < 4; ++j) Ainv[i][j] = M[i][4 + j];
}

__global__ void moog_prologue(const float* __restrict__ gf,
                              const float* __restrict__ gr,
                              const float* __restrict__ gain,
                              const float* __restrict__ alpha,
                              float* __restrict__ ws) {
    const double k  = 1.0 / SAMPLE_RATE;
    const double w  = 2.0 * M_PI * (double)gf[0] * F_PARAM;
    const double grv = (double)gr[0];
    const double al  = (double)alpha[0];
    const double gn  = (double)gain[0];

    double A[4][4] = {
        { -w, 0.0, 0.0, -4.0 * w * grv * R_PARAM },
        {  w,  -w, 0.0, 0.0 },
        { 0.0,  w,  -w, 0.0 },
        { 0.0, 0.0,  w,  -w }
    };

    double kA2[4][4];
    for (int i = 0; i < 4; ++i)
        for (int j = 0; j < 4; ++j) kA2[i][j] = 0.5 * k * A[i][j];

    double Mlhs[4][4];
    for (int i = 0; i < 4; ++i)
        for (int j = 0; j < 4; ++j)
            Mlhs[i][j] = ((i == j) ? 1.0 : 0.0) - kA2[i][j] * al;

    double Minv[4][4];
    inv4x4(Mlhs, Minv);

    double Mfwd[4][4];
    for (int i = 0; i < 4; ++i)
        for (int j = 0; j < 4; ++j)
            Mfwd[i][j] = ((i == j) ? 1.0 : 0.0) + kA2[i][j] * (2.0 - al);

    double Mc[4][4];
    for (int i = 0; i < 4; ++i)
        for (int j = 0; j < 4; ++j) {
            double s = 0.0;
            for (int m = 0; m < 4; ++m) s += Minv[i][m] * Mfwd[m][j];
            Mc[i][j] = s;
        }

    double kb2_0 = 0.5 * k * w;
    double ba0  = kb2_0 * al;
    double b1m0 = kb2_0 * (1.0 - 0.5 * al);

    for (int i = 0; i < 4; ++i) {
        for (int j = 0; j < 4; ++j) ws[4 * i + j] = (float)Mc[i][j];
        ws[16 + i] = (float)(Minv[i][0] * ba0);
        ws[20 + i] = (float)(Minv[i][0] * b1m0);
    }
    ws[24] = (float)gn;
}

// ---------------------------------------------------------------------------
// v3 main: every global stream is 16 B/lane AND lane-contiguous.
// Block of 256 threads handles 1024 samples.
//   - u/u1 read as contiguous quads, redistributed via LDS.
//   - u passthrough stored directly from the loaded quad.
//   - x in/out: thread t does samples k*256+t (k=0..3) -> contiguous f32x4.
//   - y staged in LDS, stored as contiguous quads.
// out layout: [0,B) = y_n ; [B,5B) = x_n ; [5B,6B) = u_n copy
// Requires B % 4 == 0.
// ---------------------------------------------------------------------------
__global__ __launch_bounds__(256) void moog_main_v3(
        const f32x4* __restrict__ u4,
        const f32x4* __restrict__ x4,
        const f32x4* __restrict__ u14,
        const float* __restrict__ ws,
        float* __restrict__ out,
        int B) {
    __shared__ float c[25];
    __shared__ float su[1024];
    __shared__ float su1[1024];
    __shared__ float sy[1024];

    int t = threadIdx.x;
    if (t < 25) c[t] = ws[t];

    int nq = B >> 2;                 // total quads
    int qb = blockIdx.x << 8;        // first quad of this block
    int q  = qb + t;
    bool valid = q < nq;

    f32x4* ou = (f32x4*)(out + 5 * (size_t)B);
    if (valid) {
        f32x4 u  = u4[q];
        f32x4 u1 = u14[q];
        *(f32x4*)&su[4 * t]  = u;
        *(f32x4*)&su1[4 * t] = u1;
        __builtin_nontemporal_store(u, &ou[q]);   // u_n passthrough, straight back out
    }
    __syncthreads();

    int sbase = qb << 2;             // first sample of this block
    f32x4* ox = (f32x4*)(out + (size_t)B);

    #pragma unroll
    for (int k = 0; k < 4; ++k) {
        int idx = (k << 8) + t;      // local sample in [0,1024)
        int s = sbase + idx;         // global sample
        if (s < B) {
            f32x4 x = x4[s];
            float u  = su[idx];
            float u1 = su1[idx];

            // Expression order identical to the verified scalar kernel.
            float r0 = c[0]  * x.x + c[1]  * x.y + c[2]  * x.z + c[3]  * x.w + c[16] * u + c[20] * u1;
            float r1 = c[4]  * x.x + c[5]  * x.y + c[6]  * x.z + c[7]  * x.w + c[17] * u + c[21] * u1;
            float r2 = c[8]  * x.x + c[9]  * x.y + c[10] * x.z + c[11] * x.w + c[18] * u + c[22] * u1;
            float r3 = c[12] * x.x + c[13] * x.y + c[14] * x.z + c[15] * x.w + c[19] * u + c[23] * u1;

            f32x4 xv = {r0, r1, r2, r3};
            __builtin_nontemporal_store(xv, &ox[s]);
            sy[idx] = c[24] * r3;
        }
    }
    __syncthreads();

    if (valid) {
        f32x4 yq = *(f32x4*)&sy[4 * t];
        __builtin_nontemporal_store(yq, &((f32x4*)out)[q]);
    }
}

// ---------------------------------------------------------------------------
// Scalar fallback (the original verified kernel) for B % 4 != 0.
// ---------------------------------------------------------------------------
__global__ __launch_bounds__(256) void moog_main(
        const float*  __restrict__ u_n,
        const float4* __restrict__ x_n1,
        const float*  __restrict__ u_n1,
        const float*  __restrict__ ws,
        float* __restrict__ out,
        int B) {
    __shared__ float c[25];
    int t = threadIdx.x;
    if (t < 25) c[t] = ws[t];
    __syncthreads();

    int i = blockIdx.x * blockDim.x + t;
    if (i >= B) return;

    float4 x = x_n1[i];
    float u  = u_n[i];
    float u1 = u_n1[i];

    float r0 = c[0]  * x.x + c[1]  * x.y + c[2]  * x.z + c[3]  * x.w + c[16] * u + c[20] * u1;
    float r1 = c[4]  * x.x + c[5]  * x.y + c[6]  * x.z + c[7]  * x.w + c[17] * u + c[21] * u1;
    float r2 = c[8]  * x.x + c[9]  * x.y + c[10] * x.z + c[11] * x.w + c[18] * u + c[22] * u1;
    float r3 = c[12] * x.x + c[13] * x.y + c[14] * x.z + c[15] * x.w + c[19] * u + c[23] * u1;

    out[i] = c[24] * r3;
    float* ox = out + (size_t)B + 4 * (size_t)i;
    ox[0] = r0; ox[1] = r1; ox[2] = r2; ox[3] = r3;
    out[5 * (size_t)B + i] = u;
}

extern "C" void kernel_launch(void* const* d_in, const int* in_sizes, int n_in,
                              void* d_out, int out_size, void* d_ws, size_t ws_size,
                              hipStream_t stream) {
    const float* u_n   = (const float*)d_in[0];
    const float* x_n1  = (const float*)d_in[1];
    const float* u_n1  = (const float*)d_in[2];
    const float* gf    = (const float*)d_in[3];
    const float* gr    = (const float*)d_in[4];
    const float* gain  = (const float*)d_in[5];
    const float* alpha = (const float*)d_in[6];

    int B = in_sizes[0];
    float* ws = (float*)d_ws;

    moog_prologue<<<1, 1, 0, stream>>>(gf, gr, gain, alpha, ws);

    int block = 256;
    if ((B & 3) == 0) {
        int nq = B >> 2;
        int grid = (nq + block - 1) / block;   // 1024 samples per block
        moog_main_v3<<<grid, block, 0, stream>>>((const f32x4*)u_n, (const f32x4*)x_n1,
                                                 (const f32x4*)u_n1, ws,
                                                 (float*)d_out, B);
    } else {
        int grid = (B + block - 1) / block;
        moog_main<<<grid, block, 0, stream>>>(u_n, (const float4*)x_n1, u_n1, ws,
                                              (float*)d_out, B);
    }
}